// Round 15
// baseline (1968.452 us; speedup 1.0000x reference)
//
#include <hip/hip_runtime.h>
#include <hip/hip_bf16.h>

// HMM backward recursion, B=32, T=256, H=1024, V=50257.
// y_s[b,i] = N_{s-1}[b] + log( sum_j expA[i,j] * Y_{s-1}[b,j] ) + e_t[b,i]
// Y_s = exp(y_s - N_s), N_s = max_i y_{s-1}[b,i] (one-step-stale upper bound).
// Round-13 proven substrate: 16 persistent worker WGs + 8192 fused gather
// blocks, sc0sc1 exchange, per-wave flags, barrier-free step loop.
// This round: k_expA fused into worker init (alpha -> expf -> bf16 -> LDS
// directly, same swizzled layout); one fewer dispatch, no Abf round-trip.

#define Hdim 1024
#define Bdim 32
#define Tdim 256
#define Vdim 50257
#define NWG  16
#define SLICE 64
#define NGATHER (Tdim * Bdim)              // 8192

typedef __attribute__((ext_vector_type(8))) __bf16 bf16x8;
typedef __attribute__((ext_vector_type(4))) float  f32x4;
typedef __attribute__((ext_vector_type(4))) unsigned u32x4;

// workspace layout (bytes)
#define OFF_YBUF  0                          // [2][16][4096B] = 131072
#define OFF_PSUM  (OFF_YBUF + 131072)        // 32 f32 (pad 128)
#define OFF_RBUF  (OFF_PSUM + 128)           // 32 f32 (pad 128)
#define OFF_WREC  (OFF_RBUF + 128)           // [2][16][4] x 64B = 8192
#define OFF_FLG   (OFF_WREC + 8192)          // [2][64] x 64B = 8192
#define OFF_ERDY  (OFF_FLG + 8192)           // 256 counters x 64B = 16384
#define OFF_GRD   (OFF_ERDY + 16384)         // grand counter (pad 128)
#define OFF_END0  (OFF_GRD + 128)
#define OFF_E     (((OFF_END0) + 4095) & ~4095)
#define WS_E_NEED ((size_t)OFF_E + (size_t)Tdim * Bdim * Hdim * 4)

// LDS carve
#define SM_A       131072                    // 64 rows x 1024 bf16 (swizzled)
#define SMEM_BYTES (SM_A + 256)

// ---- sc0 sc1 (device-scope, cache-bypass) access helpers ----
__device__ __forceinline__ void st_b16_sc(void* p, unsigned v) {
    asm volatile("global_store_short %0, %1, off sc0 sc1" :: "v"(p), "v"(v) : "memory");
}
__device__ __forceinline__ void st_b32_sc(void* p, unsigned v) {
    asm volatile("global_store_dword %0, %1, off sc0 sc1" :: "v"(p), "v"(v) : "memory");
}
__device__ __forceinline__ void st_b128_sc(void* p, u32x4 v) {
    asm volatile("global_store_dwordx4 %0, %1, off sc0 sc1" :: "v"(p), "v"(v) : "memory");
}
__device__ __forceinline__ u32x4 ld_b128_sc(const void* p) {
    u32x4 r;
    asm volatile("global_load_dwordx4 %0, %1, off sc0 sc1" : "=v"(r) : "v"(p) : "memory");
    return r;
}
__device__ __forceinline__ float ld_f32_sc(const void* p) {
    float r;
    asm volatile("global_load_dword %0, %1, off sc0 sc1" : "=v"(r) : "v"(p) : "memory");
    return r;
}
__device__ __forceinline__ unsigned ld_u32sync_sc(const void* p) {
    unsigned r;
    asm volatile("global_load_dword %0, %1, off sc0 sc1\n\ts_waitcnt vmcnt(0)"
                 : "=v"(r) : "v"(p) : "memory");
    return r;
}
__device__ __forceinline__ void waitcnt_vm0() {
    asm volatile("s_waitcnt vmcnt(0)" ::: "memory");
    __builtin_amdgcn_sched_barrier(0);
}
__device__ __forceinline__ void waitcnt_vm32() {
    asm volatile("s_waitcnt vmcnt(32)" ::: "memory");
    __builtin_amdgcn_sched_barrier(0);
}

// compiler-load e (init + no-E fallback)
__device__ __forceinline__ void load_e(const float* __restrict__ E,
                                       const float* __restrict__ beta,
                                       const int* __restrict__ x,
                                       int t, int b0, int i0, int useE, float e[2][4]) {
    if (useE) {
        #pragma unroll
        for (int u = 0; u < 2; ++u)
            #pragma unroll
            for (int r = 0; r < 4; ++r)
                e[u][r] = E[((size_t)t * Bdim + (b0 + r)) * Hdim + i0 + u * 16];
    } else {
        int xv[4];
        #pragma unroll
        for (int r = 0; r < 4; ++r) xv[r] = x[(b0 + r) * Tdim + t];
        #pragma unroll
        for (int u = 0; u < 2; ++u)
            #pragma unroll
            for (int r = 0; r < 4; ++r)
                e[u][r] = beta[(size_t)(i0 + u * 16) * Vdim + xv[r]];
    }
}

// Per-WAVE publish (round-7 exact): Y direct from regs (8 b16 stores/lane),
// per-b maxes as one b128 (li==0), own vm0 drain, own flag. No barrier.
__device__ __forceinline__ void publish_wave(const float y[2][4], const float Gc[4],
                                             char* Yblk, char* wrec_pw, char* flg_pw,
                                             int li, int g, int np, int b0,
                                             unsigned seq) {
    float mx[4];
    #pragma unroll
    for (int r = 0; r < 4; ++r) {
        #pragma unroll
        for (int u = 0; u < 2; ++u) {
            float Yn = __expf(y[u][r] - Gc[r]);
            __bf16 h = (__bf16)Yn;
            unsigned hv = (unsigned)__builtin_bit_cast(unsigned short, h);
            st_b16_sc(Yblk + (b0 + r) * 128 + (np * 32 + u * 16 + li) * 2, hv);
        }
        float m = fmaxf(y[0][r], y[1][r]);
        m = fmaxf(m, __shfl_xor(m, 1, 16));
        m = fmaxf(m, __shfl_xor(m, 2, 16));
        m = fmaxf(m, __shfl_xor(m, 4, 16));
        m = fmaxf(m, __shfl_xor(m, 8, 16));
        mx[r] = m;
    }
    if (li == 0) {
        f32x4 mv = {mx[0], mx[1], mx[2], mx[3]};
        st_b128_sc(wrec_pw + g * 16, __builtin_bit_cast(u32x4, mv));
    }
    asm volatile("s_waitcnt vmcnt(0)" ::: "memory");
    if ((threadIdx.x & 63) == 0) st_b32_sc(flg_pw, seq);
}

// Worker-side E readiness gate: no-op once grand counter hit NGATHER.
__device__ __forceinline__ void poll_eready(const char* erdy, const char* grd,
                                            int t, int* edone) {
    if (*edone) return;
    if (ld_u32sync_sc(grd) >= (unsigned)NGATHER) { *edone = 1; return; }
    const char* ep = erdy + (size_t)t * 64;
    while (ld_u32sync_sc(ep) < (unsigned)Bdim) {}
}

template<int USEE>
__launch_bounds__(256, 1)
__global__ void k_hmm(const int* __restrict__ x,
                      const float* __restrict__ beta,
                      const float* __restrict__ gamma,
                      const float* __restrict__ alpha,
                      char* __restrict__ Yb,        // [2][16][4096B]
                      char* __restrict__ wrec,      // [2][16][4] x 64B
                      char* __restrict__ flg,       // [2][64] x 64B
                      char* __restrict__ erdy,      // 256 x 64B
                      char* __restrict__ grd,       // grand counter
                      float* __restrict__ Psum,
                      float* __restrict__ Rbuf,
                      float* __restrict__ Ebuf)
{
    // ---------------- gather role (blocks >= NWG) ----------------
    if (USEE && blockIdx.x >= NWG) {
        const int idx = blockIdx.x - NWG;
        const int t   = (Tdim - 1) - (idx >> 5);   // high t first
        const int b   = idx & 31;
        const int xv  = x[b * Tdim + t];
        const int i   = threadIdx.x * 4;
        f32x4 v;
        v[0] = beta[(size_t)(i + 0) * Vdim + xv];
        v[1] = beta[(size_t)(i + 1) * Vdim + xv];
        v[2] = beta[(size_t)(i + 2) * Vdim + xv];
        v[3] = beta[(size_t)(i + 3) * Vdim + xv];
        st_b128_sc(Ebuf + ((size_t)t * Bdim + b) * Hdim + i,
                   __builtin_bit_cast(u32x4, v));
        asm volatile("s_waitcnt vmcnt(0)" ::: "memory");
        __syncthreads();
        if (threadIdx.x == 0) {
            atomicAdd((unsigned*)(erdy + (size_t)t * 64), 1u);
            atomicAdd((unsigned*)grd, 1u);
        }
        return;
    }

    // ---------------- worker role (round-13 exact core) ----------------
    extern __shared__ char smem[];
    char* Asl = smem;

    const int p   = blockIdx.x;
    const int tid = threadIdx.x;
    const int w   = tid >> 6;
    const int l   = tid & 63;
    const int g   = l >> 4;
    const int li  = l & 15;
    const int mb  = w & 1;
    const int np  = w >> 1;
    const int b0  = mb * 16 + g * 4;
    const int i0  = p * SLICE + np * 32 + li;

    int edone = USEE ? 0 : 1;

    // ---- stage A slice into LDS: alpha f32 -> expf -> bf16, XOR-swizzled.
    // (k_expA fused here: each WG converts its own 64 rows; coalesced 32B
    // reads per thread, identical LDS layout to the old Abf staging.)
    #pragma unroll
    for (int rep = 0; rep < 32; ++rep) {
        int flat = rep * 256 + tid;          // 16B-LDS-chunk index
        int row  = flat >> 7;                // 0..63
        int c16  = flat & 127;               // chunk within row
        const float* ap = alpha + (size_t)(p * 64 + row) * Hdim + c16 * 8;
        float4 v0 = *(const float4*)(ap);
        float4 v1 = *(const float4*)(ap + 4);
        union { __bf16 h[8]; uint4 u; } cv;
        cv.h[0] = (__bf16)__expf(v0.x);
        cv.h[1] = (__bf16)__expf(v0.y);
        cv.h[2] = (__bf16)__expf(v0.z);
        cv.h[3] = (__bf16)__expf(v0.w);
        cv.h[4] = (__bf16)__expf(v1.x);
        cv.h[5] = (__bf16)__expf(v1.y);
        cv.h[6] = (__bf16)__expf(v1.z);
        cv.h[7] = (__bf16)__expf(v1.w);
        int off = (row * 2048 + c16 * 16) ^ ((row & 7) << 4);
        *(uint4*)(Asl + off) = cv.u;
    }
    __syncthreads();    // only barrier in the worker (A staging)

    // ---- init: y0 = e[:, T-1], publish per-wave ----
    poll_eready(erdy, grd, Tdim - 1, &edone);
    poll_eready(erdy, grd, Tdim - 2, &edone);
    {
        float y0[2][4];
        load_e(Ebuf, beta, x, Tdim - 1, b0, i0, USEE, y0);
        float Gc0[4] = {0.f, 0.f, 0.f, 0.f};
        publish_wave(y0, Gc0, Yb + p * 4096,
                     wrec + (size_t)p * 256 + w * 64,
                     flg + (size_t)(p * 4 + w) * 64,
                     li, g, np, b0, 1u);
    }

    float Nprev[4] = {0.f, 0.f, 0.f, 0.f};
    float ereg[2][4];
    load_e(Ebuf, beta, x, Tdim - 2, b0, i0, USEE, ereg);

    for (int s = 1; s < Tdim; ++s) {
        const int t     = Tdim - 1 - s;
        const int par_r = (s - 1) & 1;
        const int par_w = s & 1;

        // prefetch next step's e (gate on gather readiness while needed);
        // drain BEFORE polling flags so the detect loop never waits on it
        float eregN[2][4];
        if (s < Tdim - 1) {
            poll_eready(erdy, grd, t - 1, &edone);
            load_e(Ebuf, beta, x, t - 1, b0, i0, USEE, eregN);
        }
        float gl[2] = {0.f, 0.f};
        if (s == Tdim - 1) { gl[0] = gamma[i0]; gl[1] = gamma[i0 + 16]; }
        waitcnt_vm0();

        // ---- poll all 64 producer-wave flags (each wave independently) ----
        {
            const char* fp = flg + (size_t)par_r * 4096 + l * 64;
            while (!__all((int)(ld_u32sync_sc(fp) >= (unsigned)s))) {}
        }

        // ---- issue Y loads (32 b128), then wrec loads (32 f32, lanes<32) ----
        const char* Ybase = Yb + (size_t)par_r * (NWG * 4096);
        const char* yrow  = Ybase + (mb * 16 + li) * 128 + g * 16;
        u32x4 yreg[32];
        #pragma unroll
        for (int kc = 0; kc < 32; ++kc)
            yreg[kc] = ld_b128_sc(yrow + (kc >> 1) * 4096 + (kc & 1) * 64);

        float gmv[32];
        {
            const char* wbase = wrec + (size_t)par_r * 4096;
            if (l < 32) {
                int bmb = l >> 4;          // 16-block of b
                int idx = (l & 15) * 4;
                #pragma unroll
                for (int q = 0; q < 16; ++q) {
                    gmv[2 * q]     = ld_f32_sc(wbase + q * 256 + bmb * 64 + idx);
                    gmv[2 * q + 1] = ld_f32_sc(wbase + q * 256 + (bmb + 2) * 64 + idx);
                }
            }
        }

        waitcnt_vm32();   // Y loads (oldest 32) done; wrec still in flight

        // ---- S[b, i-slice] = sum_j expA[i,j] * Y[b,j] ----
        f32x4 acc0 = {0.f, 0.f, 0.f, 0.f}, acc1 = {0.f, 0.f, 0.f, 0.f};
        {
            const int ia = np * 32 + li;
            const int ib = ia + 16;
            const int basea = ia * 2048 + g * 16, xa = (ia & 7) << 4;
            const int baseb = ib * 2048 + g * 16, xb = (ib & 7) << 4;
            #pragma unroll
            for (int kc = 0; kc < 32; ++kc) {
                bf16x8 af0 = *(const bf16x8*)(Asl + ((basea + kc * 64) ^ xa));
                bf16x8 af1 = *(const bf16x8*)(Asl + ((baseb + kc * 64) ^ xb));
                bf16x8 yf  = __builtin_bit_cast(bf16x8, yreg[kc]);
                acc0 = __builtin_amdgcn_mfma_f32_16x16x32_bf16(yf, af0, acc0, 0, 0, 0);
                acc1 = __builtin_amdgcn_mfma_f32_16x16x32_bf16(yf, af1, acc1, 0, 0, 0);
            }
        }

        waitcnt_vm0();    // wrec loads done

        // per-b global max in registers + wave-local broadcast (no LDS)
        float gm = -3.0e38f;
        if (l < 32) {
            #pragma unroll
            for (int q = 0; q < 32; ++q) gm = fmaxf(gm, gmv[q]);
        }
        float Gcur[4];
        #pragma unroll
        for (int r = 0; r < 4; ++r) Gcur[r] = __shfl(gm, b0 + r);

        float yv[2][4];
        #pragma unroll
        for (int r = 0; r < 4; ++r) {
            yv[0][r] = Nprev[r] + __logf(acc0[r]) + ereg[0][r];
            yv[1][r] = Nprev[r] + __logf(acc1[r]) + ereg[1][r];
        }

        if (s < Tdim - 1) {
            publish_wave(yv, Gcur,
                         Yb + (size_t)par_w * (NWG * 4096) + p * 4096,
                         wrec + (size_t)par_w * 4096 + (size_t)p * 256 + w * 64,
                         flg + (size_t)par_w * 4096 + (size_t)(p * 4 + w) * 64,
                         li, g, np, b0, (unsigned)(s + 1));
            #pragma unroll
            for (int r = 0; r < 4; ++r) Nprev[r] = Gcur[r];
            #pragma unroll
            for (int u = 0; u < 2; ++u)
                #pragma unroll
                for (int r = 0; r < 4; ++r) ereg[u][r] = eregN[u][r];
        } else {
            #pragma unroll
            for (int r = 0; r < 4; ++r) {
                float pa = __expf(gl[0] + yv[0][r] - Gcur[r])
                         + __expf(gl[1] + yv[1][r] - Gcur[r]);
                pa += __shfl_xor(pa, 1, 16);
                pa += __shfl_xor(pa, 2, 16);
                pa += __shfl_xor(pa, 4, 16);
                pa += __shfl_xor(pa, 8, 16);
                if (li == 0) {
                    atomicAdd(&Psum[b0 + r], pa);
                    if (p == 0) Rbuf[b0 + r] = Gcur[r];
                }
            }
        }
    }
}

__global__ void k_final(const float* __restrict__ Psum, const float* __restrict__ Rbuf,
                        float* __restrict__ out) {
    int b = threadIdx.x;
    if (b < 32) out[b] = Rbuf[b] + __logf(Psum[b]);
}

extern "C" void kernel_launch(void* const* d_in, const int* in_sizes, int n_in,
                              void* d_out, int out_size, void* d_ws, size_t ws_size,
                              hipStream_t stream) {
    const int*   x     = (const int*)d_in[0];
    const float* alpha = (const float*)d_in[1];
    const float* beta  = (const float*)d_in[2];
    const float* gamma = (const float*)d_in[3];

    char* ws = (char*)d_ws;
    char*   Yb   = ws + OFF_YBUF;
    float*  Psum = (float*)(ws + OFF_PSUM);
    float*  Rbuf = (float*)(ws + OFF_RBUF);
    char*   wrec = ws + OFF_WREC;
    char*   flg  = ws + OFF_FLG;
    char*   erdy = ws + OFF_ERDY;
    char*   grd  = ws + OFF_GRD;
    float*  Ebuf = (float*)(ws + OFF_E);

    int useE = (ws_size >= WS_E_NEED) ? 1 : 0;

    // zero Psum/Rbuf/wrec/flags/Eready/grand every launch
    (void)hipMemsetAsync(ws + OFF_PSUM, 0, OFF_END0 - OFF_PSUM, stream);

    if (useE) {
        (void)hipFuncSetAttribute((const void*)k_hmm<1>, hipFuncAttributeMaxDynamicSharedMemorySize, SMEM_BYTES);
        hipLaunchKernelGGL(k_hmm<1>, dim3(NWG + NGATHER), dim3(256), SMEM_BYTES, stream,
                           x, beta, gamma, alpha, Yb, wrec, flg, erdy, grd, Psum, Rbuf, Ebuf);
    } else {
        (void)hipFuncSetAttribute((const void*)k_hmm<0>, hipFuncAttributeMaxDynamicSharedMemorySize, SMEM_BYTES);
        hipLaunchKernelGGL(k_hmm<0>, dim3(NWG), dim3(256), SMEM_BYTES, stream,
                           x, beta, gamma, alpha, Yb, wrec, flg, erdy, grd, Psum, Rbuf, (float*)nullptr);
    }

    hipLaunchKernelGGL(k_final, dim3(1), dim3(64), 0, stream, Psum, Rbuf, (float*)d_out);
}

// Round 16
// 1941.918 us; speedup vs baseline: 1.0137x; 1.0137x over previous
//
#include <hip/hip_runtime.h>
#include <hip/hip_bf16.h>

// HMM backward recursion, B=32, T=256, H=1024, V=50257.
// y_s[b,i] = N_{s-1}[b] + log( sum_j expA[i,j] * Y_{s-1}[b,j] ) + e_t[b,i]
// Y_s = exp(y_s - N_s), N_s = max_i y_{s-1}[b,i] (one-step-stale upper bound).
// Round-15 substrate (16 persistent worker WGs + 8192 fused gather blocks,
// sc0sc1 exchange, barrier-free step loop, fused expA staging).
// This round: PACKED per-WG flag lines — the 4 wave-flags of each producer
// WG live in one 64B line (4 dwords); consumer polls all 64 flags with 16
// line requests per iteration instead of 64, cutting poll queueing at L3.

#define Hdim 1024
#define Bdim 32
#define Tdim 256
#define Vdim 50257
#define NWG  16
#define SLICE 64
#define NGATHER (Tdim * Bdim)              // 8192

typedef __attribute__((ext_vector_type(8))) __bf16 bf16x8;
typedef __attribute__((ext_vector_type(4))) float  f32x4;
typedef __attribute__((ext_vector_type(4))) unsigned u32x4;

// workspace layout (bytes)
#define OFF_YBUF  0                          // [2][16][4096B] = 131072
#define OFF_PSUM  (OFF_YBUF + 131072)        // 32 f32 (pad 128)
#define OFF_RBUF  (OFF_PSUM + 128)           // 32 f32 (pad 128)
#define OFF_WREC  (OFF_RBUF + 128)           // [2][16][4] x 64B = 8192
#define OFF_FLG   (OFF_WREC + 8192)          // [2][16] lines x 64B = 2048
#define OFF_ERDY  (OFF_FLG + 2048)           // 256 counters x 64B = 16384
#define OFF_GRD   (OFF_ERDY + 16384)         // grand counter (pad 128)
#define OFF_END0  (OFF_GRD + 128)
#define OFF_E     (((OFF_END0) + 4095) & ~4095)
#define WS_E_NEED ((size_t)OFF_E + (size_t)Tdim * Bdim * Hdim * 4)

// LDS carve
#define SM_A       131072                    // 64 rows x 1024 bf16 (swizzled)
#define SMEM_BYTES (SM_A + 256)

// ---- sc0 sc1 (device-scope, cache-bypass) access helpers ----
__device__ __forceinline__ void st_b16_sc(void* p, unsigned v) {
    asm volatile("global_store_short %0, %1, off sc0 sc1" :: "v"(p), "v"(v) : "memory");
}
__device__ __forceinline__ void st_b32_sc(void* p, unsigned v) {
    asm volatile("global_store_dword %0, %1, off sc0 sc1" :: "v"(p), "v"(v) : "memory");
}
__device__ __forceinline__ void st_b128_sc(void* p, u32x4 v) {
    asm volatile("global_store_dwordx4 %0, %1, off sc0 sc1" :: "v"(p), "v"(v) : "memory");
}
__device__ __forceinline__ u32x4 ld_b128_sc(const void* p) {
    u32x4 r;
    asm volatile("global_load_dwordx4 %0, %1, off sc0 sc1" : "=v"(r) : "v"(p) : "memory");
    return r;
}
__device__ __forceinline__ u32x4 ld_b128sync_sc(const void* p) {
    u32x4 r;
    asm volatile("global_load_dwordx4 %0, %1, off sc0 sc1\n\ts_waitcnt vmcnt(0)"
                 : "=v"(r) : "v"(p) : "memory");
    return r;
}
__device__ __forceinline__ float ld_f32_sc(const void* p) {
    float r;
    asm volatile("global_load_dword %0, %1, off sc0 sc1" : "=v"(r) : "v"(p) : "memory");
    return r;
}
__device__ __forceinline__ unsigned ld_u32sync_sc(const void* p) {
    unsigned r;
    asm volatile("global_load_dword %0, %1, off sc0 sc1\n\ts_waitcnt vmcnt(0)"
                 : "=v"(r) : "v"(p) : "memory");
    return r;
}
__device__ __forceinline__ void waitcnt_vm0() {
    asm volatile("s_waitcnt vmcnt(0)" ::: "memory");
    __builtin_amdgcn_sched_barrier(0);
}
__device__ __forceinline__ void waitcnt_vm32() {
    asm volatile("s_waitcnt vmcnt(32)" ::: "memory");
    __builtin_amdgcn_sched_barrier(0);
}

// compiler-load e (init + no-E fallback)
__device__ __forceinline__ void load_e(const float* __restrict__ E,
                                       const float* __restrict__ beta,
                                       const int* __restrict__ x,
                                       int t, int b0, int i0, int useE, float e[2][4]) {
    if (useE) {
        #pragma unroll
        for (int u = 0; u < 2; ++u)
            #pragma unroll
            for (int r = 0; r < 4; ++r)
                e[u][r] = E[((size_t)t * Bdim + (b0 + r)) * Hdim + i0 + u * 16];
    } else {
        int xv[4];
        #pragma unroll
        for (int r = 0; r < 4; ++r) xv[r] = x[(b0 + r) * Tdim + t];
        #pragma unroll
        for (int u = 0; u < 2; ++u)
            #pragma unroll
            for (int r = 0; r < 4; ++r)
                e[u][r] = beta[(size_t)(i0 + u * 16) * Vdim + xv[r]];
    }
}

// Per-WAVE publish: Y direct from regs (8 b16 stores/lane), per-b maxes as
// one b128 (li==0), own vm0 drain, own flag DWORD in the WG's packed line.
__device__ __forceinline__ void publish_wave(const float y[2][4], const float Gc[4],
                                             char* Yblk, char* wrec_pw, char* flg_dw,
                                             int li, int g, int np, int b0,
                                             unsigned seq) {
    float mx[4];
    #pragma unroll
    for (int r = 0; r < 4; ++r) {
        #pragma unroll
        for (int u = 0; u < 2; ++u) {
            float Yn = __expf(y[u][r] - Gc[r]);
            __bf16 h = (__bf16)Yn;
            unsigned hv = (unsigned)__builtin_bit_cast(unsigned short, h);
            st_b16_sc(Yblk + (b0 + r) * 128 + (np * 32 + u * 16 + li) * 2, hv);
        }
        float m = fmaxf(y[0][r], y[1][r]);
        m = fmaxf(m, __shfl_xor(m, 1, 16));
        m = fmaxf(m, __shfl_xor(m, 2, 16));
        m = fmaxf(m, __shfl_xor(m, 4, 16));
        m = fmaxf(m, __shfl_xor(m, 8, 16));
        mx[r] = m;
    }
    if (li == 0) {
        f32x4 mv = {mx[0], mx[1], mx[2], mx[3]};
        st_b128_sc(wrec_pw + g * 16, __builtin_bit_cast(u32x4, mv));
    }
    asm volatile("s_waitcnt vmcnt(0)" ::: "memory");
    if ((threadIdx.x & 63) == 0) st_b32_sc(flg_dw, seq);
}

// Worker-side E readiness gate: no-op once grand counter hit NGATHER.
__device__ __forceinline__ void poll_eready(const char* erdy, const char* grd,
                                            int t, int* edone) {
    if (*edone) return;
    if (ld_u32sync_sc(grd) >= (unsigned)NGATHER) { *edone = 1; return; }
    const char* ep = erdy + (size_t)t * 64;
    while (ld_u32sync_sc(ep) < (unsigned)Bdim) {}
}

template<int USEE>
__launch_bounds__(256, 1)
__global__ void k_hmm(const int* __restrict__ x,
                      const float* __restrict__ beta,
                      const float* __restrict__ gamma,
                      const float* __restrict__ alpha,
                      char* __restrict__ Yb,        // [2][16][4096B]
                      char* __restrict__ wrec,      // [2][16][4] x 64B
                      char* __restrict__ flg,       // [2][16] lines x 64B
                      char* __restrict__ erdy,      // 256 x 64B
                      char* __restrict__ grd,       // grand counter
                      float* __restrict__ Psum,
                      float* __restrict__ Rbuf,
                      float* __restrict__ Ebuf)
{
    // ---------------- gather role (blocks >= NWG) ----------------
    if (USEE && blockIdx.x >= NWG) {
        const int idx = blockIdx.x - NWG;
        const int t   = (Tdim - 1) - (idx >> 5);   // high t first
        const int b   = idx & 31;
        const int xv  = x[b * Tdim + t];
        const int i   = threadIdx.x * 4;
        f32x4 v;
        v[0] = beta[(size_t)(i + 0) * Vdim + xv];
        v[1] = beta[(size_t)(i + 1) * Vdim + xv];
        v[2] = beta[(size_t)(i + 2) * Vdim + xv];
        v[3] = beta[(size_t)(i + 3) * Vdim + xv];
        st_b128_sc(Ebuf + ((size_t)t * Bdim + b) * Hdim + i,
                   __builtin_bit_cast(u32x4, v));
        asm volatile("s_waitcnt vmcnt(0)" ::: "memory");
        __syncthreads();
        if (threadIdx.x == 0) {
            atomicAdd((unsigned*)(erdy + (size_t)t * 64), 1u);
            atomicAdd((unsigned*)grd, 1u);
        }
        return;
    }

    // ---------------- worker role ----------------
    extern __shared__ char smem[];
    char* Asl = smem;

    const int p   = blockIdx.x;
    const int tid = threadIdx.x;
    const int w   = tid >> 6;
    const int l   = tid & 63;
    const int g   = l >> 4;
    const int li  = l & 15;
    const int mb  = w & 1;
    const int np  = w >> 1;
    const int b0  = mb * 16 + g * 4;
    const int i0  = p * SLICE + np * 32 + li;

    int edone = USEE ? 0 : 1;

    // ---- stage A slice into LDS: alpha f32 -> expf -> bf16, XOR-swizzled ----
    #pragma unroll
    for (int rep = 0; rep < 32; ++rep) {
        int flat = rep * 256 + tid;
        int row  = flat >> 7;
        int c16  = flat & 127;
        const float* ap = alpha + (size_t)(p * 64 + row) * Hdim + c16 * 8;
        float4 v0 = *(const float4*)(ap);
        float4 v1 = *(const float4*)(ap + 4);
        union { __bf16 h[8]; uint4 u; } cv;
        cv.h[0] = (__bf16)__expf(v0.x);
        cv.h[1] = (__bf16)__expf(v0.y);
        cv.h[2] = (__bf16)__expf(v0.z);
        cv.h[3] = (__bf16)__expf(v0.w);
        cv.h[4] = (__bf16)__expf(v1.x);
        cv.h[5] = (__bf16)__expf(v1.y);
        cv.h[6] = (__bf16)__expf(v1.z);
        cv.h[7] = (__bf16)__expf(v1.w);
        int off = (row * 2048 + c16 * 16) ^ ((row & 7) << 4);
        *(uint4*)(Asl + off) = cv.u;
    }
    __syncthreads();    // only barrier in the worker (A staging)

    // ---- init: y0 = e[:, T-1], publish per-wave ----
    poll_eready(erdy, grd, Tdim - 1, &edone);
    poll_eready(erdy, grd, Tdim - 2, &edone);
    {
        float y0[2][4];
        load_e(Ebuf, beta, x, Tdim - 1, b0, i0, USEE, y0);
        float Gc0[4] = {0.f, 0.f, 0.f, 0.f};
        publish_wave(y0, Gc0, Yb + p * 4096,
                     wrec + (size_t)p * 256 + w * 64,
                     flg + (size_t)p * 64 + w * 4,
                     li, g, np, b0, 1u);
    }

    float Nprev[4] = {0.f, 0.f, 0.f, 0.f};
    float ereg[2][4];
    load_e(Ebuf, beta, x, Tdim - 2, b0, i0, USEE, ereg);

    for (int s = 1; s < Tdim; ++s) {
        const int t     = Tdim - 1 - s;
        const int par_r = (s - 1) & 1;
        const int par_w = s & 1;

        // prefetch next step's e (gate on gather readiness while needed);
        // drain BEFORE polling flags so the detect loop never waits on it
        float eregN[2][4];
        if (s < Tdim - 1) {
            poll_eready(erdy, grd, t - 1, &edone);
            load_e(Ebuf, beta, x, t - 1, b0, i0, USEE, eregN);
        }
        float gl[2] = {0.f, 0.f};
        if (s == Tdim - 1) { gl[0] = gamma[i0]; gl[1] = gamma[i0 + 16]; }
        waitcnt_vm0();

        // ---- poll packed flag lines: lane l -> WG line (l&15), u32x4 holds
        //      that WG's 4 wave flags. 16 line requests/wave/iteration. ----
        {
            const char* fp = flg + (size_t)par_r * 1024 + (l & 15) * 64;
            for (;;) {
                u32x4 f = ld_b128sync_sc(fp);
                int ok = (f[0] >= (unsigned)s) & (f[1] >= (unsigned)s)
                       & (f[2] >= (unsigned)s) & (f[3] >= (unsigned)s);
                if (__all(ok)) break;
            }
        }

        // ---- issue Y loads (32 b128), then wrec loads (32 f32, lanes<32) ----
        const char* Ybase = Yb + (size_t)par_r * (NWG * 4096);
        const char* yrow  = Ybase + (mb * 16 + li) * 128 + g * 16;
        u32x4 yreg[32];
        #pragma unroll
        for (int kc = 0; kc < 32; ++kc)
            yreg[kc] = ld_b128_sc(yrow + (kc >> 1) * 4096 + (kc & 1) * 64);

        float gmv[32];
        {
            const char* wbase = wrec + (size_t)par_r * 4096;
            if (l < 32) {
                int bmb = l >> 4;          // 16-block of b
                int idx = (l & 15) * 4;
                #pragma unroll
                for (int q = 0; q < 16; ++q) {
                    gmv[2 * q]     = ld_f32_sc(wbase + q * 256 + bmb * 64 + idx);
                    gmv[2 * q + 1] = ld_f32_sc(wbase + q * 256 + (bmb + 2) * 64 + idx);
                }
            }
        }

        waitcnt_vm32();   // Y loads (oldest 32) done; wrec still in flight

        // ---- S[b, i-slice] = sum_j expA[i,j] * Y[b,j] ----
        f32x4 acc0 = {0.f, 0.f, 0.f, 0.f}, acc1 = {0.f, 0.f, 0.f, 0.f};
        {
            const int ia = np * 32 + li;
            const int ib = ia + 16;
            const int basea = ia * 2048 + g * 16, xa = (ia & 7) << 4;
            const int baseb = ib * 2048 + g * 16, xb = (ib & 7) << 4;
            #pragma unroll
            for (int kc = 0; kc < 32; ++kc) {
                bf16x8 af0 = *(const bf16x8*)(Asl + ((basea + kc * 64) ^ xa));
                bf16x8 af1 = *(const bf16x8*)(Asl + ((baseb + kc * 64) ^ xb));
                bf16x8 yf  = __builtin_bit_cast(bf16x8, yreg[kc]);
                acc0 = __builtin_amdgcn_mfma_f32_16x16x32_bf16(yf, af0, acc0, 0, 0, 0);
                acc1 = __builtin_amdgcn_mfma_f32_16x16x32_bf16(yf, af1, acc1, 0, 0, 0);
            }
        }

        waitcnt_vm0();    // wrec loads done

        // per-b global max in registers + wave-local broadcast (no LDS)
        float gm = -3.0e38f;
        if (l < 32) {
            #pragma unroll
            for (int q = 0; q < 32; ++q) gm = fmaxf(gm, gmv[q]);
        }
        float Gcur[4];
        #pragma unroll
        for (int r = 0; r < 4; ++r) Gcur[r] = __shfl(gm, b0 + r);

        float yv[2][4];
        #pragma unroll
        for (int r = 0; r < 4; ++r) {
            yv[0][r] = Nprev[r] + __logf(acc0[r]) + ereg[0][r];
            yv[1][r] = Nprev[r] + __logf(acc1[r]) + ereg[1][r];
        }

        if (s < Tdim - 1) {
            publish_wave(yv, Gcur,
                         Yb + (size_t)par_w * (NWG * 4096) + p * 4096,
                         wrec + (size_t)par_w * 4096 + (size_t)p * 256 + w * 64,
                         flg + (size_t)par_w * 1024 + (size_t)p * 64 + w * 4,
                         li, g, np, b0, (unsigned)(s + 1));
            #pragma unroll
            for (int r = 0; r < 4; ++r) Nprev[r] = Gcur[r];
            #pragma unroll
            for (int u = 0; u < 2; ++u)
                #pragma unroll
                for (int r = 0; r < 4; ++r) ereg[u][r] = eregN[u][r];
        } else {
            #pragma unroll
            for (int r = 0; r < 4; ++r) {
                float pa = __expf(gl[0] + yv[0][r] - Gcur[r])
                         + __expf(gl[1] + yv[1][r] - Gcur[r]);
                pa += __shfl_xor(pa, 1, 16);
                pa += __shfl_xor(pa, 2, 16);
                pa += __shfl_xor(pa, 4, 16);
                pa += __shfl_xor(pa, 8, 16);
                if (li == 0) {
                    atomicAdd(&Psum[b0 + r], pa);
                    if (p == 0) Rbuf[b0 + r] = Gcur[r];
                }
            }
        }
    }
}

__global__ void k_final(const float* __restrict__ Psum, const float* __restrict__ Rbuf,
                        float* __restrict__ out) {
    int b = threadIdx.x;
    if (b < 32) out[b] = Rbuf[b] + __logf(Psum[b]);
}

extern "C" void kernel_launch(void* const* d_in, const int* in_sizes, int n_in,
                              void* d_out, int out_size, void* d_ws, size_t ws_size,
                              hipStream_t stream) {
    const int*   x     = (const int*)d_in[0];
    const float* alpha = (const float*)d_in[1];
    const float* beta  = (const float*)d_in[2];
    const float* gamma = (const float*)d_in[3];

    char* ws = (char*)d_ws;
    char*   Yb   = ws + OFF_YBUF;
    float*  Psum = (float*)(ws + OFF_PSUM);
    float*  Rbuf = (float*)(ws + OFF_RBUF);
    char*   wrec = ws + OFF_WREC;
    char*   flg  = ws + OFF_FLG;
    char*   erdy = ws + OFF_ERDY;
    char*   grd  = ws + OFF_GRD;
    float*  Ebuf = (float*)(ws + OFF_E);

    int useE = (ws_size >= WS_E_NEED) ? 1 : 0;

    // zero Psum/Rbuf/wrec/flags/Eready/grand every launch
    (void)hipMemsetAsync(ws + OFF_PSUM, 0, OFF_END0 - OFF_PSUM, stream);

    if (useE) {
        (void)hipFuncSetAttribute((const void*)k_hmm<1>, hipFuncAttributeMaxDynamicSharedMemorySize, SMEM_BYTES);
        hipLaunchKernelGGL(k_hmm<1>, dim3(NWG + NGATHER), dim3(256), SMEM_BYTES, stream,
                           x, beta, gamma, alpha, Yb, wrec, flg, erdy, grd, Psum, Rbuf, Ebuf);
    } else {
        (void)hipFuncSetAttribute((const void*)k_hmm<0>, hipFuncAttributeMaxDynamicSharedMemorySize, SMEM_BYTES);
        hipLaunchKernelGGL(k_hmm<0>, dim3(NWG), dim3(256), SMEM_BYTES, stream,
                           x, beta, gamma, alpha, Yb, wrec, flg, erdy, grd, Psum, Rbuf, (float*)nullptr);
    }

    hipLaunchKernelGGL(k_final, dim3(1), dim3(64), 0, stream, Psum, Rbuf, (float*)d_out);
}